// Round 17
// baseline (154.296 us; speedup 1.0000x reference)
//
#include <hip/hip_runtime.h>
#include <hip/hip_bf16.h>

typedef __attribute__((ext_vector_type(8))) short bf16x8;   // 8 bf16 = 4 VGPR (MFMA A/B frag)
typedef __attribute__((ext_vector_type(4))) float f32x4;    // MFMA C/D frag

#define DEVI __device__ __forceinline__
#define AS1 __attribute__((address_space(1)))
#define AS3 __attribute__((address_space(3)))

constexpr int SEQ_   = 2048;
constexpr int HEADS  = 16;
constexpr int DHEAD  = 64;
constexpr int DMODEL = 1024;

DEVI unsigned short f2bf(float x) {
  __hip_bfloat16 h = __float2bfloat16(x);   // RNE
  return __builtin_bit_cast(unsigned short, h);
}

DEVI f32x4 MFMA(bf16x8 a, bf16x8 b, f32x4 c) {
  return __builtin_amdgcn_mfma_f32_16x16x32_bf16(a, b, c, 0, 0, 0);
}

DEVI unsigned int cvtpk(float lo, float hi) {   // dst.lo16=bf16(lo), dst.hi16=bf16(hi)
  unsigned int u;
  asm("v_cvt_pk_bf16_f32 %0, %1, %2" : "=v"(u) : "v"(lo), "v"(hi));
  return u;
}

DEVI float exp2v(float x) {                     // raw v_exp_f32: D = 2^S0 (1 VALU op)
  float y;
  asm("v_exp_f32 %0, %1" : "=v"(y) : "v"(x));
  return y;
}

// ---------------------------------------------------------------- convert ---
// One launch: y=0..2 -> query/key/value (4M elems each); y=3 -> concatenated
// Wq|Wk|Wv|Er regions (3*1M + 128K elems; all region bounds are /8).
__global__ void conv_all_kernel(const float* q, const float* k, const float* v,
                                const float* Wq, const float* Wk, const float* Wv,
                                const float* Er,
                                unsigned short* Xq, unsigned short* Xk,
                                unsigned short* Xv,
                                unsigned short* Wqb, unsigned short* Wkb,
                                unsigned short* Wvb, unsigned short* Erb) {
  const int y = blockIdx.y;
  const int i = (blockIdx.x * 256 + threadIdx.x) * 8;
  const float* s;
  unsigned short* d;
  int off = i;
  if (y < 3) {
    if (i >= 2 * SEQ_ * DMODEL) return;
    s = (y == 0) ? q : (y == 1) ? k : v;
    d = (y == 0) ? Xq : (y == 1) ? Xk : Xv;
  } else {
    constexpr int NW = DMODEL * DMODEL;           // 1048576 (/8)
    if (i >= 3 * NW + SEQ_ * DHEAD) return;
    if (i < NW)          { s = Wq; d = Wqb; }
    else if (i < 2 * NW) { s = Wk; d = Wkb; off = i - NW; }
    else if (i < 3 * NW) { s = Wv; d = Wvb; off = i - 2 * NW; }
    else                 { s = Er; d = Erb; off = i - 3 * NW; }
  }
  const float4* p = (const float4*)(s + off);
  float4 v0 = p[0], v1 = p[1];
  union { unsigned short u[8]; bf16x8 v; } t;
  t.u[0] = f2bf(v0.x); t.u[1] = f2bf(v0.y); t.u[2] = f2bf(v0.z); t.u[3] = f2bf(v0.w);
  t.u[4] = f2bf(v1.x); t.u[5] = f2bf(v1.y); t.u[6] = f2bf(v1.z); t.u[7] = f2bf(v1.w);
  *(bf16x8*)(d + off) = t.v;
}

// ------------------------------------------------------------- projection ---
// z==0 (Q): out (b,h,s,d), pre-scaled by 0.125*log2(e) (exp2 softmax fold).
// z==1 (K): 4KB tiles (per 32 t) in MFMA fragment order.
// z==2 (V): 8KB tiles (per 64 t) frag order with t' = 4*(t&15) + (t>>4)
//           permutation (matches attn's b64 P-write order).
__global__ __launch_bounds__(256) void proj3_kernel(
    const unsigned short* __restrict__ X0, const unsigned short* __restrict__ X1,
    const unsigned short* __restrict__ X2,
    const unsigned short* __restrict__ W0, const unsigned short* __restrict__ W1,
    const unsigned short* __restrict__ W2,
    const float* __restrict__ bi0, const float* __restrict__ bi1,
    const float* __restrict__ bi2,
    unsigned short* __restrict__ o0, unsigned short* __restrict__ o1,
    unsigned short* __restrict__ o2) {
  const int z = blockIdx.z;
  const unsigned short* X = (z == 0) ? X0 : (z == 1) ? X1 : X2;
  const unsigned short* W = (z == 0) ? W0 : (z == 1) ? W1 : W2;
  const float* bias        = (z == 0) ? bi0 : (z == 1) ? bi1 : bi2;
  unsigned short* out      = (z == 0) ? o0 : (z == 1) ? o1 : o2;

  __shared__ unsigned short Abuf[2][128 * 32];
  __shared__ unsigned short Bbuf[2][128 * 32];
  const int tid  = threadIdx.x;
  const int lane = tid & 63, wv = tid >> 6;
  const int q = lane >> 4, r = lane & 15;
  const int wrow = wv >> 1, wcol = wv & 1;
  const int rowA0 = blockIdx.x * 128, colB0 = blockIdx.y * 128;

  const char* Ag = (const char*)(X + (size_t)rowA0 * DMODEL);
  const char* Bg = (const char*)(W + (size_t)colB0 * DMODEL);

  f32x4 acc[4][4] = {};

  auto stage = [&](int ks, int buf) {
    const int koff = ks * 64;
#pragma unroll
    for (int i = 0; i < 2; ++i) {
      const int b   = (i * 256 + tid) * 16;
      const int row = b >> 6, col = b & 63;
      __builtin_amdgcn_global_load_lds(
          (const AS1 void*)(Ag + (size_t)row * (DMODEL * 2) + koff + col),
          (AS3 void*)((char*)&Abuf[buf][0] + i * 4096 + wv * 1024),
          16, 0, 0);
      __builtin_amdgcn_global_load_lds(
          (const AS1 void*)(Bg + (size_t)row * (DMODEL * 2) + koff + col),
          (AS3 void*)((char*)&Bbuf[buf][0] + i * 4096 + wv * 1024),
          16, 0, 0);
    }
  };

  stage(0, 0);
  for (int ks = 0; ks < 32; ++ks) {
    __syncthreads();
    if (ks + 1 < 32) stage(ks + 1, (ks + 1) & 1);
    const unsigned short* A  = &Abuf[ks & 1][0];
    const unsigned short* Bt = &Bbuf[ks & 1][0];
    bf16x8 af[4], bfr[4];
#pragma unroll
    for (int t = 0; t < 4; ++t) {
      af[t]  = *(const bf16x8*)(A  + (wrow * 64 + t * 16 + r) * 32 + q * 8);
      bfr[t] = *(const bf16x8*)(Bt + (wcol * 64 + t * 16 + r) * 32 + q * 8);
    }
#pragma unroll
    for (int m = 0; m < 4; ++m)
#pragma unroll
      for (int n = 0; n < 4; ++n)
        acc[m][n] = MFMA(af[m], bfr[n], acc[m][n]);
  }

#pragma unroll
  for (int m = 0; m < 4; ++m) {
#pragma unroll
    for (int n = 0; n < 4; ++n) {
      const int e  = colB0 + wcol * 64 + n * 16 + r;
      const float bv = bias[e];
      const int h = e >> 6, dd = e & 63;
      const int nrow0 = rowA0 + wrow * 64 + m * 16 + q * 4;
      const int bb = nrow0 >> 11, ss0 = nrow0 & 2047;
      const size_t bh = (size_t)(bb * HEADS + h);
      if (z == 0) {
#pragma unroll
        for (int j = 0; j < 4; ++j)
          out[(bh * SEQ_ + (ss0 + j)) * DHEAD + dd] =
              f2bf((acc[m][n][j] + bv) * 0.1803368801111244f);   // 0.125*log2e
      } else if (z == 1) {
#pragma unroll
        for (int j = 0; j < 4; ++j) {
          const int s = ss0 + j;
          const size_t off = (bh * 64 + (size_t)(s >> 5)) * 2048
                           + (size_t)(((dd >> 5) * 2 + ((s >> 4) & 1)) * 512)
                           + (size_t)(((((dd & 31) >> 3) << 4) + (s & 15)) * 8)
                           + (dd & 7);
          out[off] = f2bf(acc[m][n][j] + bv);
        }
      } else {
        // V: 8KB tile per 64 t, t' = 4*(t&15) + (t>>4)
#pragma unroll
        for (int j = 0; j < 4; ++j) {
          const int s = ss0 + j;
          const int tile64 = s >> 6, t = s & 63;
          const int tp = 4 * (t & 15) + (t >> 4);
          const int tc = tp >> 5, u = tp & 31;
          const int ln = ((u >> 3) << 4) | (dd & 15);
          const size_t off = (bh * 32 + (size_t)tile64) * 4096
                           + (size_t)(tc * 2048 + (dd >> 4) * 512 + ln * 8 + (u & 7));
          out[off] = f2bf(acc[m][n][j] + bv);
        }
      }
    }
  }
}

// -------------------------------------------------------------- attention ---
// R16 body, restructured for 3 blocks/CU: RING-2 LDS (stage issued AFTER the
// barrier -> alternate buffer is provably idle; s_waitcnt vmcnt(8) BEFORE the
// barrier guarantees the current tile's stage landed) -> LDS 49.4KB.
// 768 blocks x 256 thr: pair p timeline = [tileA=15-p: 32-2p iters] ++
// [tileB=p: 2p+2 iters] (34 total), segments [0,12),[12,23),[23,34) -> every
// block 11-12 iters, all resident at 3 blocks/CU. All segments write bf16
// partial (O,l) slots; reduce sums the statically-valid slots per tile.
struct ErSet { bf16x8 e[8]; };

__global__ __launch_bounds__(256, 2) void attn_kernel(
    const unsigned short* __restrict__ qb, const unsigned short* __restrict__ kt,
    const unsigned short* __restrict__ vt, const unsigned short* __restrict__ Er,
    unsigned short* __restrict__ pO, float* __restrict__ pL) {
  __shared__ unsigned short k_lds[2][4096];     // 8KB/buf (2x 4KB frag tiles)
  __shared__ unsigned short v_lds[2][4096];     // 8KB/buf (one 64-t permuted tile)
  __shared__ unsigned short p_lds[4][32][68];   // [s][t'] b64-written P

  const int tid  = threadIdx.x;
  const int lane = tid & 63, wv = tid >> 6;     // 4 waves
  const int q = lane >> 4, r = lane & 15;

  const int lid = blockIdx.x;
  const int xcd = lid & 7, idx = lid >> 3;      // 96 per XCD
  const int bh  = (xcd << 2) | (idx & 3);       // 4 bh pinned per XCD L2
  const int rest = idx >> 2;                    // 0..23
  const int p = rest / 3, seg = rest - p * 3;   // pair 0..7, segment 0..2

  const unsigned short* qbh = qb + (size_t)bh * SEQ_ * DHEAD;
  const char* ktb = (const char*)(kt + (size_t)bh * 64 * 2048);
  const char* vtb = (const char*)(vt + (size_t)bh * 32 * 4096);
  const f32x4 zero4 = {0.f, 0.f, 0.f, 0.f};

  const char* sgbase = (wv < 2) ? ktb : vtb;
  char* sdst0 = (char*)((wv < 2) ? &k_lds[0][0] : &v_lds[0][0]);
  const int shalf = (wv & 1) * 4096;
  const int soff  = lane * 16;

  auto stageKV = [&](int it, int buf) {         // 4 vmem ops, always
    const char* src = sgbase + (size_t)it * 8192 + shalf + soff;
    char* dst = sdst0 + buf * 8192 + shalf;
#pragma unroll
    for (int c = 0; c < 4; ++c)
      __builtin_amdgcn_global_load_lds((const AS1 void*)(src + c * 1024),
                                       (AS3 void*)(dst + c * 1024), 16, 0, 0);
  };

  auto run_strip = [&](int T, int it0, int it1, unsigned short* po, float* pl) {
    const int s0 = T * 128 + wv * 32;
    __syncthreads();                            // strip boundary: full drain
    stageKV(it0, 0);                            // lands during prologue

    bf16x8 qf[2][2];
#pragma unroll
    for (int rt = 0; rt < 2; ++rt) {
      qf[rt][0] = *(const bf16x8*)(qbh + (size_t)(s0 + rt * 16 + r) * DHEAD + q * 8);
      qf[rt][1] = *(const bf16x8*)(qbh + (size_t)(s0 + rt * 16 + r) * DHEAD + 32 + q * 8);
    }

    f32x4 qer[2][6];
    {                                           // lattice init: tiles 0,1
      const int lb0 = 2016 + it0 * 64 - s0;
#pragma unroll
      for (int m = 0; m < 2; ++m) {
        int l = lb0 + m * 16 + r; l = l < 2047 ? l : 2047;
        l = l < 0 ? 0 : l;
        bf16x8 e0 = *(const bf16x8*)(Er + (size_t)l * DHEAD + q * 8);
        bf16x8 e1 = *(const bf16x8*)(Er + (size_t)l * DHEAD + 32 + q * 8);
#pragma unroll
        for (int rt = 0; rt < 2; ++rt)
          qer[rt][m] = MFMA(qf[rt][1], e1, MFMA(qf[rt][0], e0, zero4));
      }
    }

    auto loadE = [&](ErSet& es, int it) {       // 8 vmem ops, always
      const int lb = 2016 + it * 64 - s0;
#pragma unroll
      for (int mi = 0; mi < 4; ++mi) {
        int l = lb + 32 + mi * 16 + r;
        l = l < 2047 ? l : 2047;
        es.e[mi * 2 + 0] = *(const bf16x8*)(Er + (size_t)l * DHEAD + q * 8);
        es.e[mi * 2 + 1] = *(const bf16x8*)(Er + (size_t)l * DHEAD + 32 + q * 8);
      }
    };

    f32x4 oacc[2][4] = {};
    float lpart[2][4] = {};

    auto body = [&](int it, int cur, const ErSet& es) {
      const int t0 = it * 64;
      if (t0 > s0 + 31) return;                 // masked tail (no barriers inside)
      const unsigned short* KL = &k_lds[cur][0];
      const unsigned short* VL = &v_lds[cur][0];

      bf16x8 kf[4][2];
#pragma unroll
      for (int ct = 0; ct < 4; ++ct)
#pragma unroll
        for (int kc = 0; kc < 2; ++kc)
          kf[ct][kc] = *(const bf16x8*)(KL + (ct >> 1) * 2048 + (kc * 2 + (ct & 1)) * 512 + lane * 8);

      f32x4 s4[2][4];
      __builtin_amdgcn_s_setprio(1);
#pragma unroll
      for (int rt = 0; rt < 2; ++rt)
#pragma unroll
        for (int ct = 0; ct < 4; ++ct)
          s4[rt][ct] = MFMA(qf[rt][1], kf[ct][1], MFMA(qf[rt][0], kf[ct][0], zero4));
#pragma unroll
      for (int rt = 0; rt < 2; ++rt)
#pragma unroll
        for (int mi = 0; mi < 4; ++mi)
          qer[rt][2 + mi] = MFMA(qf[rt][1], es.e[mi * 2 + 1],
                                 MFMA(qf[rt][0], es.e[mi * 2 + 0], zero4));
      __builtin_amdgcn_s_setprio(0);

      const int d0 = t0 - s0;
#pragma unroll
      for (int rt = 0; rt < 2; ++rt) {
        const int a = 1 - rt;                   // lattice window base tile
#pragma unroll
        for (int j = 0; j < 4; ++j) {
          unsigned int pkA = cvtpk(qer[rt][a][j],     qer[rt][a + 1][j]);
          unsigned int pkB = cvtpk(qer[rt][a + 2][j], qer[rt][a + 3][j]);
          const float  s5f = qer[rt][a + 4][j];
          const int srcl = (q << 4) | ((15 + r - q * 4 - j) & 15);
          unsigned int A = (unsigned int)__shfl((int)pkA, srcl);
          unsigned int B = (unsigned int)__shfl((int)pkB, srcl);
          const float g4 = __shfl(s5f, srcl);
          const float g0 = __builtin_bit_cast(float, A << 16);
          const float g1 = __builtin_bit_cast(float, A & 0xffff0000u);
          const float g2 = __builtin_bit_cast(float, B << 16);
          const float g3 = __builtin_bit_cast(float, B & 0xffff0000u);
          const bool hi = (r > q * 4 + j);
          const float b0 = hi ? g1 : g0;
          const float b1 = hi ? g2 : g1;
          const float b2 = hi ? g3 : g2;
          const float b3 = hi ? g4 : g3;
          const int A_ = rt * 16 + q * 4 + j - r - d0;   // keep iff ct*16 <= A_
          const float p0 = (A_ >= 0)  ? exp2v(s4[rt][0][j] + b0) : 0.f;
          const float p1 = (A_ >= 16) ? exp2v(s4[rt][1][j] + b1) : 0.f;
          const float p2 = (A_ >= 32) ? exp2v(s4[rt][2][j] + b2) : 0.f;
          const float p3 = (A_ >= 48) ? exp2v(s4[rt][3][j] + b3) : 0.f;
          lpart[rt][j] += (p0 + p1) + (p2 + p3);
          const int sl = rt * 16 + q * 4 + j;
          const unsigned long long pw =
              (unsigned long long)cvtpk(p0, p1) |
              ((unsigned long long)cvtpk(p2, p3) << 32);
          *(unsigned long long*)&p_lds[wv][sl][4 * r] = pw;   // t' = 4r+ct
        }
      }

      bf16x8 vf[4][2];
#pragma unroll
      for (int dc = 0; dc < 4; ++dc)
#pragma unroll
        for (int tc = 0; tc < 2; ++tc)
          vf[dc][tc] = *(const bf16x8*)(VL + tc * 2048 + dc * 512 + lane * 8);
      __builtin_amdgcn_s_setprio(1);
#pragma unroll
      for (int rt = 0; rt < 2; ++rt) {
        bf16x8 pf0 = *(const bf16x8*)(&p_lds[wv][rt * 16 + r][0] + q * 8);
        bf16x8 pf1 = *(const bf16x8*)(&p_lds[wv][rt * 16 + r][0] + 32 + q * 8);
#pragma unroll
        for (int dc = 0; dc < 4; ++dc)
          oacc[rt][dc] = MFMA(pf1, vf[dc][1], MFMA(pf0, vf[dc][0], oacc[rt][dc]));
      }
      __builtin_amdgcn_s_setprio(0);

#pragma unroll
      for (int rt = 0; rt < 2; ++rt) { qer[rt][0] = qer[rt][4]; qer[rt][1] = qer[rt][5]; }
    };

    ErSet eA, eB;
    loadE(eA, it0);

    // ring-2 main loop: wait(current stage landed) BEFORE barrier; stage the
    // ALTERNATE buffer AFTER the barrier (its readers all passed the barrier).
    int it = it0, cur = 0;
    while (true) {
      asm volatile("s_waitcnt vmcnt(8)\n\ts_barrier" ::: "memory");
      {
        const int itn = (it + 1 < it1) ? it + 1 : it1 - 1;
        stageKV(itn, cur ^ 1);
        loadE(eB, itn);
      }
      body(it, cur, eA);
      cur ^= 1;
      if (++it >= it1) break;
      asm volatile("s_waitcnt vmcnt(8)\n\ts_barrier" ::: "memory");
      {
        const int itn = (it + 1 < it1) ? it + 1 : it1 - 1;
        stageKV(itn, cur ^ 1);
        loadE(eA, itn);
      }
      body(it, cur, eB);
      cur ^= 1;
      if (++it >= it1) break;
    }

    // epilogue: bf16 partial O + f32 partial l (unnormalized)
#pragma unroll
    for (int rt = 0; rt < 2; ++rt)
#pragma unroll
      for (int j = 0; j < 4; ++j) {
        float ls = lpart[rt][j];
#pragma unroll
        for (int d = 1; d < 16; d <<= 1) ls += __shfl_xor(ls, d);
        const int row = wv * 32 + rt * 16 + q * 4 + j;
#pragma unroll
        for (int dc = 0; dc < 4; ++dc)
          po[(size_t)row * 64 + dc * 16 + r] = f2bf(oacc[rt][dc][j]);
        if (r == 0) pl[row] = ls;
      }
  };

  // segment [a,b) of the pair timeline; tile A part then tile B part.
  const int a  = (seg == 0) ? 0 : (seg == 1) ? 12 : 23;
  const int b  = (seg == 0) ? 12 : (seg == 1) ? 23 : 34;
  const int LA = 32 - 2 * p;                    // tile A iter count
  const int TAt = 15 - p, TBt = p;

  if (a < LA) {
    const size_t slot = ((size_t)(bh * 16 + TAt)) * 3 + seg;
    const int e = (b < LA) ? b : LA;
    run_strip(TAt, a, e, pO + slot * 8192, pL + slot * 128);
  }
  if (b > LA) {
    const size_t slot = ((size_t)(bh * 16 + TBt)) * 3 + seg;
    const int s = (a > LA) ? a - LA : 0;
    run_strip(TBt, s, b - LA, pO + slot * 8192, pL + slot * 128);
  }
}

// ---------------------------------------------------------------- reduce ----
// out = sum(valid bf16 partial O slots) / sum(valid l slots) per 128-row tile.
// Valid segments per tile T (static): T>=11:{0,1,2}; 8..10:{0,1};
// 5..7:{1,2}; <=4:{2}.
__global__ __launch_bounds__(256) void reduce_kernel(const unsigned short* __restrict__ pO,
                                                     const float* __restrict__ pL,
                                                     float* __restrict__ out) {
  const int slot = blockIdx.x;                  // bh*16 + T
  const int bh = slot >> 4, T = slot & 15;
  const int bb = bh >> 4, hh = bh & 15;
  const int tid = threadIdx.x;
  const int row = tid >> 1, half = (tid & 1) * 32;

  const int s_lo = (T >= 8) ? 0 : (T >= 5) ? 1 : 2;
  const int s_hi = (T >= 11) ? 3 : (T >= 8) ? 2 : 3;

  float l = 0.f;
  float acc[32] = {};
  for (int s = s_lo; s < s_hi; ++s) {
    const size_t sb = (size_t)slot * 3 + s;
    l += pL[sb * 128 + row];
    const unsigned short* src = pO + sb * 8192 + row * 64 + half;
#pragma unroll
    for (int c = 0; c < 4; ++c) {
      union { bf16x8 v; unsigned short u[8]; } w;
      w.v = *(const bf16x8*)(src + c * 8);
#pragma unroll
      for (int e = 0; e < 8; ++e)
        acc[c * 8 + e] += __builtin_bit_cast(float, (unsigned int)w.u[e] << 16);
    }
  }

  const float inv = 1.0f / l;
  float* dst = out + ((size_t)(bb * SEQ_) + T * 128 + row) * DMODEL + hh * DHEAD + half;
#pragma unroll
  for (int c = 0; c < 8; ++c) {
    float4 o;
    o.x = acc[c * 4 + 0] * inv; o.y = acc[c * 4 + 1] * inv;
    o.z = acc[c * 4 + 2] * inv; o.w = acc[c * 4 + 3] * inv;
    ((float4*)dst)[c] = o;
  }
}

// ------------------------------------------------------------------ launch ---
extern "C" void kernel_launch(void* const* d_in, const int* in_sizes, int n_in,
                              void* d_out, int out_size, void* d_ws, size_t ws_size,
                              hipStream_t stream) {
  const float* query = (const float*)d_in[0];
  const float* key   = (const float*)d_in[1];
  const float* value = (const float*)d_in[2];
  const float* Wq    = (const float*)d_in[3];
  const float* bq    = (const float*)d_in[4];
  const float* Wk    = (const float*)d_in[5];
  const float* bk    = (const float*)d_in[6];
  const float* Wv    = (const float*)d_in[7];
  const float* bv    = (const float*)d_in[8];
  const float* Er    = (const float*)d_in[9];

  char* ws = (char*)d_ws;
  unsigned short* qb   = (unsigned short*)(ws + (0u  << 20));  // 8MB
  unsigned short* ktil = (unsigned short*)(ws + (8u  << 20));  // 8MB
  unsigned short* vtil = (unsigned short*)(ws + (16u << 20));  // 8MB
  unsigned short* pO   = (unsigned short*)(ws + (24u << 20));  // 25.2MB bf16 [24,49.2) (X dead post-proj)
  float*          pL   = (float*)(ws + (50u << 20));           // 786KB (Xv tail, dead post-proj)
  unsigned short* Xq   = (unsigned short*)(ws + (32u << 20));  // proj inputs (pre-attn only)
  unsigned short* Xk   = (unsigned short*)(ws + (40u << 20));
  unsigned short* Xv   = (unsigned short*)(ws + (48u << 20));
  unsigned short* Wqb  = (unsigned short*)(ws + (56u << 20));  // 2MB
  unsigned short* Wkb  = (unsigned short*)(ws + (58u << 20));
  unsigned short* Wvb  = (unsigned short*)(ws + (60u << 20));
  unsigned short* Erb  = (unsigned short*)(ws + (62u << 20));  // 256KB

  conv_all_kernel<<<dim3(2048, 4), 256, 0, stream>>>(query, key, value,
                                                     Wq, Wk, Wv, Er,
                                                     Xq, Xk, Xv,
                                                     Wqb, Wkb, Wvb, Erb);

  proj3_kernel<<<dim3(32, 8, 3), 256, 0, stream>>>(Xq, Xk, Xv, Wqb, Wkb, Wvb,
                                                   bq, bk, bv, qb, ktil, vtil);

  attn_kernel<<<dim3(768), 256, 0, stream>>>(qb, ktil, vtil, Erb, pO, pL);

  reduce_kernel<<<dim3(512), 256, 0, stream>>>(pO, pL, (float*)d_out);
}

// Round 18
// 135.101 us; speedup vs baseline: 1.1421x; 1.1421x over previous
//
#include <hip/hip_runtime.h>
#include <hip/hip_bf16.h>

typedef __attribute__((ext_vector_type(8))) short bf16x8;   // 8 bf16 = 4 VGPR (MFMA A/B frag)
typedef __attribute__((ext_vector_type(4))) float f32x4;    // MFMA C/D frag

#define DEVI __device__ __forceinline__
#define AS1 __attribute__((address_space(1)))
#define AS3 __attribute__((address_space(3)))

constexpr int SEQ_   = 2048;
constexpr int HEADS  = 16;
constexpr int DHEAD  = 64;
constexpr int DMODEL = 1024;

DEVI unsigned short f2bf(float x) {
  __hip_bfloat16 h = __float2bfloat16(x);   // RNE
  return __builtin_bit_cast(unsigned short, h);
}

DEVI f32x4 MFMA(bf16x8 a, bf16x8 b, f32x4 c) {
  return __builtin_amdgcn_mfma_f32_16x16x32_bf16(a, b, c, 0, 0, 0);
}

DEVI unsigned int cvtpk(float lo, float hi) {   // dst.lo16=bf16(lo), dst.hi16=bf16(hi)
  unsigned int u;
  asm("v_cvt_pk_bf16_f32 %0, %1, %2" : "=v"(u) : "v"(lo), "v"(hi));
  return u;
}

DEVI float exp2v(float x) {                     // raw v_exp_f32: D = 2^S0 (1 VALU op)
  float y;
  asm("v_exp_f32 %0, %1" : "=v"(y) : "v"(x));
  return y;
}

// ---------------------------------------------------------------- convert ---
// One launch: y=0..2 -> query/key/value (4M elems each); y=3 -> concatenated
// Wq|Wk|Wv|Er regions (3*1M + 128K elems; all region bounds are /8).
__global__ void conv_all_kernel(const float* q, const float* k, const float* v,
                                const float* Wq, const float* Wk, const float* Wv,
                                const float* Er,
                                unsigned short* Xq, unsigned short* Xk,
                                unsigned short* Xv,
                                unsigned short* Wqb, unsigned short* Wkb,
                                unsigned short* Wvb, unsigned short* Erb) {
  const int y = blockIdx.y;
  const int i = (blockIdx.x * 256 + threadIdx.x) * 8;
  const float* s;
  unsigned short* d;
  int off = i;
  if (y < 3) {
    if (i >= 2 * SEQ_ * DMODEL) return;
    s = (y == 0) ? q : (y == 1) ? k : v;
    d = (y == 0) ? Xq : (y == 1) ? Xk : Xv;
  } else {
    constexpr int NW = DMODEL * DMODEL;           // 1048576 (/8)
    if (i >= 3 * NW + SEQ_ * DHEAD) return;
    if (i < NW)          { s = Wq; d = Wqb; }
    else if (i < 2 * NW) { s = Wk; d = Wkb; off = i - NW; }
    else if (i < 3 * NW) { s = Wv; d = Wvb; off = i - 2 * NW; }
    else                 { s = Er; d = Erb; off = i - 3 * NW; }
  }
  const float4* p = (const float4*)(s + off);
  float4 v0 = p[0], v1 = p[1];
  union { unsigned short u[8]; bf16x8 v; } t;
  t.u[0] = f2bf(v0.x); t.u[1] = f2bf(v0.y); t.u[2] = f2bf(v0.z); t.u[3] = f2bf(v0.w);
  t.u[4] = f2bf(v1.x); t.u[5] = f2bf(v1.y); t.u[6] = f2bf(v1.z); t.u[7] = f2bf(v1.w);
  *(bf16x8*)(d + off) = t.v;
}

// ------------------------------------------------------------- projection ---
// z==0 (Q): out (b,h,s,d), pre-scaled by 0.125*log2(e) (exp2 softmax fold).
// z==1 (K): 4KB tiles (per 32 t) in MFMA fragment order.
// z==2 (V): 8KB tiles (per 64 t) frag order with t' = 4*(t&15) + (t>>4)
//           permutation (matches attn's b64 P-write order).
__global__ __launch_bounds__(256) void proj3_kernel(
    const unsigned short* __restrict__ X0, const unsigned short* __restrict__ X1,
    const unsigned short* __restrict__ X2,
    const unsigned short* __restrict__ W0, const unsigned short* __restrict__ W1,
    const unsigned short* __restrict__ W2,
    const float* __restrict__ bi0, const float* __restrict__ bi1,
    const float* __restrict__ bi2,
    unsigned short* __restrict__ o0, unsigned short* __restrict__ o1,
    unsigned short* __restrict__ o2) {
  const int z = blockIdx.z;
  const unsigned short* X = (z == 0) ? X0 : (z == 1) ? X1 : X2;
  const unsigned short* W = (z == 0) ? W0 : (z == 1) ? W1 : W2;
  const float* bias        = (z == 0) ? bi0 : (z == 1) ? bi1 : bi2;
  unsigned short* out      = (z == 0) ? o0 : (z == 1) ? o1 : o2;

  __shared__ unsigned short Abuf[2][128 * 32];
  __shared__ unsigned short Bbuf[2][128 * 32];
  const int tid  = threadIdx.x;
  const int lane = tid & 63, wv = tid >> 6;
  const int q = lane >> 4, r = lane & 15;
  const int wrow = wv >> 1, wcol = wv & 1;
  const int rowA0 = blockIdx.x * 128, colB0 = blockIdx.y * 128;

  const char* Ag = (const char*)(X + (size_t)rowA0 * DMODEL);
  const char* Bg = (const char*)(W + (size_t)colB0 * DMODEL);

  f32x4 acc[4][4] = {};

  auto stage = [&](int ks, int buf) {
    const int koff = ks * 64;
#pragma unroll
    for (int i = 0; i < 2; ++i) {
      const int b   = (i * 256 + tid) * 16;
      const int row = b >> 6, col = b & 63;
      __builtin_amdgcn_global_load_lds(
          (const AS1 void*)(Ag + (size_t)row * (DMODEL * 2) + koff + col),
          (AS3 void*)((char*)&Abuf[buf][0] + i * 4096 + wv * 1024),
          16, 0, 0);
      __builtin_amdgcn_global_load_lds(
          (const AS1 void*)(Bg + (size_t)row * (DMODEL * 2) + koff + col),
          (AS3 void*)((char*)&Bbuf[buf][0] + i * 4096 + wv * 1024),
          16, 0, 0);
    }
  };

  stage(0, 0);
  for (int ks = 0; ks < 32; ++ks) {
    __syncthreads();
    if (ks + 1 < 32) stage(ks + 1, (ks + 1) & 1);
    const unsigned short* A  = &Abuf[ks & 1][0];
    const unsigned short* Bt = &Bbuf[ks & 1][0];
    bf16x8 af[4], bfr[4];
#pragma unroll
    for (int t = 0; t < 4; ++t) {
      af[t]  = *(const bf16x8*)(A  + (wrow * 64 + t * 16 + r) * 32 + q * 8);
      bfr[t] = *(const bf16x8*)(Bt + (wcol * 64 + t * 16 + r) * 32 + q * 8);
    }
#pragma unroll
    for (int m = 0; m < 4; ++m)
#pragma unroll
      for (int n = 0; n < 4; ++n)
        acc[m][n] = MFMA(af[m], bfr[n], acc[m][n]);
  }

#pragma unroll
  for (int m = 0; m < 4; ++m) {
#pragma unroll
    for (int n = 0; n < 4; ++n) {
      const int e  = colB0 + wcol * 64 + n * 16 + r;
      const float bv = bias[e];
      const int h = e >> 6, dd = e & 63;
      const int nrow0 = rowA0 + wrow * 64 + m * 16 + q * 4;
      const int bb = nrow0 >> 11, ss0 = nrow0 & 2047;
      const size_t bh = (size_t)(bb * HEADS + h);
      if (z == 0) {
#pragma unroll
        for (int j = 0; j < 4; ++j)
          out[(bh * SEQ_ + (ss0 + j)) * DHEAD + dd] =
              f2bf((acc[m][n][j] + bv) * 0.1803368801111244f);   // 0.125*log2e
      } else if (z == 1) {
#pragma unroll
        for (int j = 0; j < 4; ++j) {
          const int s = ss0 + j;
          const size_t off = (bh * 64 + (size_t)(s >> 5)) * 2048
                           + (size_t)(((dd >> 5) * 2 + ((s >> 4) & 1)) * 512)
                           + (size_t)(((((dd & 31) >> 3) << 4) + (s & 15)) * 8)
                           + (dd & 7);
          out[off] = f2bf(acc[m][n][j] + bv);
        }
      } else {
        // V: 8KB tile per 64 t, t' = 4*(t&15) + (t>>4)
#pragma unroll
        for (int j = 0; j < 4; ++j) {
          const int s = ss0 + j;
          const int tile64 = s >> 6, t = s & 63;
          const int tp = 4 * (t & 15) + (t >> 4);
          const int tc = tp >> 5, u = tp & 31;
          const int ln = ((u >> 3) << 4) | (dd & 15);
          const size_t off = (bh * 32 + (size_t)tile64) * 4096
                           + (size_t)(tc * 2048 + (dd >> 4) * 512 + ln * 8 + (u & 7));
          out[off] = f2bf(acc[m][n][j] + bv);
        }
      }
    }
  }
}

// -------------------------------------------------------------- attention ---
// (R16-proven structure: ring-3 counted vmcnt(12), v_exp_f32 softmax.)
// 512 blocks x 256 thr (4 waves x 32 rows = 128-row tile). Each block: 17
// contiguous iters = fh(T)=[0,T+1) of one tile + sh of its complement.
// Both halves write bf16 partial O + f32 partial l; reduce merges 2 slots.
struct ErSet { bf16x8 e[8]; };

__global__ __launch_bounds__(256, 2) void attn_kernel(
    const unsigned short* __restrict__ qb, const unsigned short* __restrict__ kt,
    const unsigned short* __restrict__ vt, const unsigned short* __restrict__ Er,
    unsigned short* __restrict__ pO, float* __restrict__ pL) {
  __shared__ unsigned short k_lds[3][4096];     // 8KB/buf (2x 4KB frag tiles)
  __shared__ unsigned short v_lds[3][4096];     // 8KB/buf (one 64-t permuted tile)
  __shared__ unsigned short p_lds[4][32][68];   // [s][t'] b64-written P

  const int tid  = threadIdx.x;
  const int lane = tid & 63, wv = tid >> 6;     // 4 waves
  const int q = lane >> 4, r = lane & 15;

  const int lid = blockIdx.x;
  const int xcd = lid & 7, idx = lid >> 3;
  const int bh  = (xcd << 2) | (idx & 3);       // 4 bh pinned per XCD L2
  const int jb  = idx >> 2;                     // 0..15
  const int p = jb >> 1, role = jb & 1;

  const unsigned short* qbh = qb + (size_t)bh * SEQ_ * DHEAD;
  const char* ktb = (const char*)(kt + (size_t)bh * 64 * 2048);
  const char* vtb = (const char*)(vt + (size_t)bh * 32 * 4096);
  const f32x4 zero4 = {0.f, 0.f, 0.f, 0.f};

  const char* sgbase = (wv < 2) ? ktb : vtb;
  char* sdst0 = (char*)((wv < 2) ? &k_lds[0][0] : &v_lds[0][0]);
  const int shalf = (wv & 1) * 4096;
  const int soff  = lane * 16;

  auto stageKV = [&](int it, int buf) {         // 4 vmem ops, always
    const char* src = sgbase + (size_t)it * 8192 + shalf + soff;
    char* dst = sdst0 + buf * 8192 + shalf;
#pragma unroll
    for (int c = 0; c < 4; ++c)
      __builtin_amdgcn_global_load_lds((const AS1 void*)(src + c * 1024),
                                       (AS3 void*)(dst + c * 1024), 16, 0, 0);
  };

  auto run_strip = [&](int T, int it0, int it1, unsigned short* po, float* pl) {
    const int s0 = T * 128 + wv * 32;
    __syncthreads();                            // drain prev strip
    stageKV(it0, 0);

    bf16x8 qf[2][2];
#pragma unroll
    for (int rt = 0; rt < 2; ++rt) {
      qf[rt][0] = *(const bf16x8*)(qbh + (size_t)(s0 + rt * 16 + r) * DHEAD + q * 8);
      qf[rt][1] = *(const bf16x8*)(qbh + (size_t)(s0 + rt * 16 + r) * DHEAD + 32 + q * 8);
    }

    f32x4 qer[2][6];
    {                                           // lattice init: tiles 0,1
      const int lb0 = 2016 + it0 * 64 - s0;
#pragma unroll
      for (int m = 0; m < 2; ++m) {
        int l = lb0 + m * 16 + r; l = l < 2047 ? l : 2047;
        bf16x8 e0 = *(const bf16x8*)(Er + (size_t)l * DHEAD + q * 8);
        bf16x8 e1 = *(const bf16x8*)(Er + (size_t)l * DHEAD + 32 + q * 8);
#pragma unroll
        for (int rt = 0; rt < 2; ++rt)
          qer[rt][m] = MFMA(qf[rt][1], e1, MFMA(qf[rt][0], e0, zero4));
      }
    }

    auto loadE = [&](ErSet& es, int it) {       // 8 vmem ops, always
      const int lb = 2016 + it * 64 - s0;
#pragma unroll
      for (int mi = 0; mi < 4; ++mi) {
        int l = lb + 32 + mi * 16 + r;
        l = l < 2047 ? l : 2047;
        es.e[mi * 2 + 0] = *(const bf16x8*)(Er + (size_t)l * DHEAD + q * 8);
        es.e[mi * 2 + 1] = *(const bf16x8*)(Er + (size_t)l * DHEAD + 32 + q * 8);
      }
    };

    f32x4 oacc[2][4] = {};
    float lpart[2][4] = {};

    auto body = [&](int it, int cur, const ErSet& es) {
      const int t0 = it * 64;
      if (t0 > s0 + 31) return;                 // masked tail (no barriers inside)
      const unsigned short* KL = &k_lds[cur][0];
      const unsigned short* VL = &v_lds[cur][0];

      bf16x8 kf[4][2];
#pragma unroll
      for (int ct = 0; ct < 4; ++ct)
#pragma unroll
        for (int kc = 0; kc < 2; ++kc)
          kf[ct][kc] = *(const bf16x8*)(KL + (ct >> 1) * 2048 + (kc * 2 + (ct & 1)) * 512 + lane * 8);

      f32x4 s4[2][4];
      __builtin_amdgcn_s_setprio(1);
#pragma unroll
      for (int rt = 0; rt < 2; ++rt)
#pragma unroll
        for (int ct = 0; ct < 4; ++ct)
          s4[rt][ct] = MFMA(qf[rt][1], kf[ct][1], MFMA(qf[rt][0], kf[ct][0], zero4));
#pragma unroll
      for (int rt = 0; rt < 2; ++rt)
#pragma unroll
        for (int mi = 0; mi < 4; ++mi)
          qer[rt][2 + mi] = MFMA(qf[rt][1], es.e[mi * 2 + 1],
                                 MFMA(qf[rt][0], es.e[mi * 2 + 0], zero4));
      __builtin_amdgcn_s_setprio(0);

      const int d0 = t0 - s0;
#pragma unroll
      for (int rt = 0; rt < 2; ++rt) {
        const int a = 1 - rt;                   // lattice window base tile
#pragma unroll
        for (int j = 0; j < 4; ++j) {
          unsigned int pkA = cvtpk(qer[rt][a][j],     qer[rt][a + 1][j]);
          unsigned int pkB = cvtpk(qer[rt][a + 2][j], qer[rt][a + 3][j]);
          const float  s5f = qer[rt][a + 4][j];
          const int srcl = (q << 4) | ((15 + r - q * 4 - j) & 15);
          unsigned int A = (unsigned int)__shfl((int)pkA, srcl);
          unsigned int B = (unsigned int)__shfl((int)pkB, srcl);
          const float g4 = __shfl(s5f, srcl);
          const float g0 = __builtin_bit_cast(float, A << 16);
          const float g1 = __builtin_bit_cast(float, A & 0xffff0000u);
          const float g2 = __builtin_bit_cast(float, B << 16);
          const float g3 = __builtin_bit_cast(float, B & 0xffff0000u);
          const bool hi = (r > q * 4 + j);
          const float b0 = hi ? g1 : g0;
          const float b1 = hi ? g2 : g1;
          const float b2 = hi ? g3 : g2;
          const float b3 = hi ? g4 : g3;
          const int A_ = rt * 16 + q * 4 + j - r - d0;   // keep iff ct*16 <= A_
          const float p0 = (A_ >= 0)  ? exp2v(s4[rt][0][j] + b0) : 0.f;
          const float p1 = (A_ >= 16) ? exp2v(s4[rt][1][j] + b1) : 0.f;
          const float p2 = (A_ >= 32) ? exp2v(s4[rt][2][j] + b2) : 0.f;
          const float p3 = (A_ >= 48) ? exp2v(s4[rt][3][j] + b3) : 0.f;
          lpart[rt][j] += (p0 + p1) + (p2 + p3);
          const int sl = rt * 16 + q * 4 + j;
          const unsigned long long pw =
              (unsigned long long)cvtpk(p0, p1) |
              ((unsigned long long)cvtpk(p2, p3) << 32);
          *(unsigned long long*)&p_lds[wv][sl][4 * r] = pw;   // t' = 4r+ct
        }
      }

      bf16x8 vf[4][2];
#pragma unroll
      for (int dc = 0; dc < 4; ++dc)
#pragma unroll
        for (int tc = 0; tc < 2; ++tc)
          vf[dc][tc] = *(const bf16x8*)(VL + tc * 2048 + dc * 512 + lane * 8);
      __builtin_amdgcn_s_setprio(1);
#pragma unroll
      for (int rt = 0; rt < 2; ++rt) {
        bf16x8 pf0 = *(const bf16x8*)(&p_lds[wv][rt * 16 + r][0] + q * 8);
        bf16x8 pf1 = *(const bf16x8*)(&p_lds[wv][rt * 16 + r][0] + 32 + q * 8);
#pragma unroll
        for (int dc = 0; dc < 4; ++dc)
          oacc[rt][dc] = MFMA(pf1, vf[dc][1], MFMA(pf0, vf[dc][0], oacc[rt][dc]));
      }
      __builtin_amdgcn_s_setprio(0);

#pragma unroll
      for (int rt = 0; rt < 2; ++rt) { qer[rt][0] = qer[rt][4]; qer[rt][1] = qer[rt][5]; }
    };

    ErSet eA, eB;
    loadE(eA, it0);

    int it = it0, cur = 0;
    while (true) {
      int nx = cur + 1; if (nx == 3) nx = 0;
      int itn = (it + 1 < it1) ? it + 1 : it1 - 1;
      stageKV(itn, nx);
      loadE(eB, itn);
      asm volatile("s_waitcnt vmcnt(12)\n\ts_barrier" ::: "memory");
      body(it, cur, eA);
      cur = nx;
      if (++it >= it1) break;
      nx = cur + 1; if (nx == 3) nx = 0;
      itn = (it + 1 < it1) ? it + 1 : it1 - 1;
      stageKV(itn, nx);
      loadE(eA, itn);
      asm volatile("s_waitcnt vmcnt(12)\n\ts_barrier" ::: "memory");
      body(it, cur, eB);
      cur = nx;
      if (++it >= it1) break;
    }

    // epilogue: bf16 partial O + f32 partial l (unnormalized)
#pragma unroll
    for (int rt = 0; rt < 2; ++rt)
#pragma unroll
      for (int j = 0; j < 4; ++j) {
        float ls = lpart[rt][j];
#pragma unroll
        for (int d = 1; d < 16; d <<= 1) ls += __shfl_xor(ls, d);
        const int row = wv * 32 + rt * 16 + q * 4 + j;
#pragma unroll
        for (int dc = 0; dc < 4; ++dc)
          po[(size_t)row * 64 + dc * 16 + r] = f2bf(oacc[rt][dc][j]);
        if (r == 0) pl[row] = ls;
      }
  };

  // block = fh(TA) + sh(TB), 17 iters total
  int TA, a1, TB, b0, b1;
  if (role == 0) { TA = 15 - p; a1 = 16 - p; TB = p;      b0 = p + 1;  b1 = 2 * p + 2; }
  else           { TA = p;      a1 = p + 1;  TB = 15 - p; b0 = 16 - p; b1 = 32 - 2 * p; }

  // slot 0 = [0,it_split) half, slot 1 = rest (role 0 owns slot0 of TA, slot1 of TB)
  run_strip(TA, 0, a1,
            pO + (((size_t)(bh * 16 + TA)) * 2 + 0) * 8192,
            pL + (((size_t)(bh * 16 + TA)) * 2 + 0) * 128);
  run_strip(TB, b0, b1,
            pO + (((size_t)(bh * 16 + TB)) * 2 + 1) * 8192,
            pL + (((size_t)(bh * 16 + TB)) * 2 + 1) * 128);
}

// ---------------------------------------------------------------- reduce ----
// out = (bf16 pO slot0 + slot1) / (l0 + l1) per 128-row tile.
__global__ __launch_bounds__(256) void reduce_kernel(const unsigned short* __restrict__ pO,
                                                     const float* __restrict__ pL,
                                                     float* __restrict__ out) {
  const int slot = blockIdx.x;                  // bh*16 + T
  const int bh = slot >> 4, T = slot & 15;
  const int bb = bh >> 4, hh = bh & 15;
  const int tid = threadIdx.x;
  const int row = tid >> 1, half = (tid & 1) * 32;

  const float l0 = pL[((size_t)slot * 2 + 0) * 128 + row];
  const float l1 = pL[((size_t)slot * 2 + 1) * 128 + row];
  const float inv = 1.0f / (l0 + l1);

  float acc[32] = {};
#pragma unroll
  for (int k = 0; k < 2; ++k) {
    const unsigned short* src = pO + ((size_t)slot * 2 + k) * 8192 + row * 64 + half;
#pragma unroll
    for (int c = 0; c < 4; ++c) {
      union { bf16x8 v; unsigned short u[8]; } w;
      w.v = *(const bf16x8*)(src + c * 8);
#pragma unroll
      for (int e = 0; e < 8; ++e)
        acc[c * 8 + e] += __builtin_bit_cast(float, (unsigned int)w.u[e] << 16);
    }
  }

  float* dst = out + ((size_t)(bb * SEQ_) + T * 128 + row) * DMODEL + hh * DHEAD + half;
#pragma unroll
  for (int c = 0; c < 8; ++c) {
    float4 o;
    o.x = acc[c * 4 + 0] * inv; o.y = acc[c * 4 + 1] * inv;
    o.z = acc[c * 4 + 2] * inv; o.w = acc[c * 4 + 3] * inv;
    ((float4*)dst)[c] = o;
  }
}

// ------------------------------------------------------------------ launch ---
extern "C" void kernel_launch(void* const* d_in, const int* in_sizes, int n_in,
                              void* d_out, int out_size, void* d_ws, size_t ws_size,
                              hipStream_t stream) {
  const float* query = (const float*)d_in[0];
  const float* key   = (const float*)d_in[1];
  const float* value = (const float*)d_in[2];
  const float* Wq    = (const float*)d_in[3];
  const float* bq    = (const float*)d_in[4];
  const float* Wk    = (const float*)d_in[5];
  const float* bk    = (const float*)d_in[6];
  const float* Wv    = (const float*)d_in[7];
  const float* bv    = (const float*)d_in[8];
  const float* Er    = (const float*)d_in[9];

  char* ws = (char*)d_ws;
  unsigned short* qb   = (unsigned short*)(ws + (0u  << 20));  // 8MB
  unsigned short* ktil = (unsigned short*)(ws + (8u  << 20));  // 8MB
  unsigned short* vtil = (unsigned short*)(ws + (16u << 20));  // 8MB
  unsigned short* pO   = (unsigned short*)(ws + (24u << 20));  // 16MB bf16 [24,40)
  float*          pL   = (float*)(ws + (40u << 20));           // 512KB
  unsigned short* Xq   = (unsigned short*)(ws + (32u << 20));  // proj inputs (pre-attn only)
  unsigned short* Xk   = (unsigned short*)(ws + (40u << 20));
  unsigned short* Xv   = (unsigned short*)(ws + (48u << 20));
  unsigned short* Wqb  = (unsigned short*)(ws + (56u << 20));  // 2MB
  unsigned short* Wkb  = (unsigned short*)(ws + (58u << 20));
  unsigned short* Wvb  = (unsigned short*)(ws + (60u << 20));
  unsigned short* Erb  = (unsigned short*)(ws + (62u << 20));  // 256KB

  conv_all_kernel<<<dim3(2048, 4), 256, 0, stream>>>(query, key, value,
                                                     Wq, Wk, Wv, Er,
                                                     Xq, Xk, Xv,
                                                     Wqb, Wkb, Wvb, Erb);

  proj3_kernel<<<dim3(32, 8, 3), 256, 0, stream>>>(Xq, Xk, Xv, Wqb, Wkb, Wvb,
                                                   bq, bk, bv, qb, ktil, vtil);

  attn_kernel<<<dim3(512), 256, 0, stream>>>(qb, ktil, vtil, Erb, pO, pL);

  reduce_kernel<<<dim3(512), 256, 0, stream>>>(pO, pL, (float*)d_out);
}